// Round 3
// baseline (325.481 us; speedup 1.0000x reference)
//
#include <hip/hip_runtime.h>
#include <math.h>

typedef unsigned short ush;
typedef short short8 __attribute__((ext_vector_type(8)));
typedef int i32x4 __attribute__((ext_vector_type(4)));
typedef int i32x16 __attribute__((ext_vector_type(16)));
typedef float f32x16 __attribute__((ext_vector_type(16)));
typedef unsigned int u32;

namespace {
constexpr int B = 4, C = 256, N = 4096, NCH = 4;
constexpr size_t PL8 = (size_t)B * N * C;              // 4 MB
constexpr size_t OFF_TH  = 0;
constexpr size_t OFF_TL  = PL8;
constexpr size_t OFF_PH  = 2 * PL8;
constexpr size_t OFF_PLO = 3 * PL8;
constexpr size_t OFF_G   = 4 * PL8;                    // bf16 [B][C][N], 8 MB
constexpr size_t FOFF    = 4 * PL8 + (size_t)B * C * N * 2;  // 24 MB
constexpr size_t F_PM = 0;
constexpr size_t F_PS = (size_t)B * NCH * N;
constexpr size_t F_M  = 2 * (size_t)B * NCH * N;

constexpr float SCL = 8.0f / 127.0f;
constexpr float S2  = SCL * SCL;
constexpr float RB  = 1.5f / 89.09545f;
constexpr float L2E = 1.44269504f;                     // log2(e)
constexpr float BA2  = 2.0f * S2 * L2E;                // bias consts pre-scaled by log2e
constexpr float BBC2 = RB * S2 * L2E;
constexpr float C1  = 1.0f / 254.0f;
constexpr float INV_SCL = 127.0f / 8.0f;
}

#define MFMAI8(a, b, c)  __builtin_amdgcn_mfma_i32_32x32x32_i8((a), (b), (c), 0, 0, 0)
#define MFMABF(a, b, c)  __builtin_amdgcn_mfma_f32_32x32x16_bf16((a), (b), (c), 0, 0, 0)

// counted-vmcnt pipeline barriers (T3+T4): never drain to 0 in steady state
#define WAITV(n) asm volatile("s_waitcnt vmcnt(" #n ")" ::: "memory")
#define WAITVL(n) asm volatile("s_waitcnt vmcnt(" #n ") lgkmcnt(0)" ::: "memory")
#define PBAR __builtin_amdgcn_s_barrier()

__device__ __forceinline__ ush f2bf(float v) {
  u32 x = __float_as_uint(v);
  return (ush)((x + 0x7FFFu + ((x >> 16) & 1u)) >> 16);
}

// shared by stats & out: MUST round identically (i32 inputs are exact).
// Returns the biased score in log2 domain (log2e folded into BA2/BBC2).
__device__ __forceinline__ float score_l2(int hh, int xx, int dxi, float dy2) {
  float u = fmaf((float)xx, C1, (float)hh);
  float dx = (float)dxi;
  float d = sqrtf(fmaf(dx, dx, dy2));
  return fmaf(d, -BBC2, BA2) * u;
}

__device__ __forceinline__ void gload16(const void* g, void* l) {
  __builtin_amdgcn_global_load_lds(
      (const __attribute__((address_space(1))) u32*)(g),
      (__attribute__((address_space(3))) u32*)(l), 16, 0, 0);
}

// ---------------- kernel 1: projections -> i8 hi/lo planes + bf16 g --------
__global__ __launch_bounds__(256) void proj_kernel(
    const float* __restrict__ x, const float* __restrict__ w_phi,
    const float* __restrict__ w_theta, const float* __restrict__ w_g,
    char* __restrict__ wsu8) {
  __shared__ float Wst[16][68];
  __shared__ float Xs[16][68];
  const int tid = threadIdx.x, tx = tid & 15, ty = tid >> 4;
  const int b = blockIdx.y / 3, p = blockIdx.y % 3;
  const int c0 = (blockIdx.x >> 6) * 64;
  const int nb = (blockIdx.x & 63) * 64;
  const float* w = (p == 0) ? w_theta : (p == 1) ? w_phi : w_g;

  float acc[4][4] = {};
  for (int kk = 0; kk < C; kk += 16) {
    {
      int r = tid >> 2, kq = (tid & 3) << 2;
      float4 v = *reinterpret_cast<const float4*>(&w[(size_t)(c0 + r) * C + kk + kq]);
      Wst[kq + 0][r] = v.x; Wst[kq + 1][r] = v.y;
      Wst[kq + 2][r] = v.z; Wst[kq + 3][r] = v.w;
    }
    {
      int k = tid >> 4, j4 = (tid & 15) << 2;
      *reinterpret_cast<float4*>(&Xs[k][j4]) =
          *reinterpret_cast<const float4*>(&x[((size_t)b * C + kk + k) * N + nb + j4]);
    }
    __syncthreads();
#pragma unroll
    for (int k2 = 0; k2 < 16; ++k2) {
      float4 av = *reinterpret_cast<const float4*>(&Wst[k2][ty << 2]);
      float4 bv = *reinterpret_cast<const float4*>(&Xs[k2][tx << 2]);
      float aa[4] = {av.x, av.y, av.z, av.w};
      float bb[4] = {bv.x, bv.y, bv.z, bv.w};
#pragma unroll
      for (int i = 0; i < 4; ++i)
#pragma unroll
        for (int j = 0; j < 4; ++j) acc[i][j] = fmaf(aa[i], bb[j], acc[i][j]);
    }
    __syncthreads();
  }

  if (p < 2) {
    char* hi = wsu8 + (p == 0 ? OFF_TH : OFF_PH) + (size_t)b * N * C;
    char* lo = wsu8 + (p == 0 ? OFF_TL : OFF_PLO) + (size_t)b * N * C;
#pragma unroll
    for (int j = 0; j < 4; ++j) {
      int n = nb + (tx << 2) + j;
      u32 ph = 0, pl = 0;
#pragma unroll
      for (int i = 0; i < 4; ++i) {
        float t = acc[i][j] * INV_SCL;
        int h = __float2int_rn(t);
        h = max(-127, min(127, h));
        int l = __float2int_rn((t - (float)h) * 254.0f);
        l = max(-127, min(127, l));
        ph |= ((u32)(h & 0xFF)) << (8 * i);
        pl |= ((u32)(l & 0xFF)) << (8 * i);
      }
      *(u32*)(hi + (size_t)n * C + c0 + (ty << 2)) = ph;
      *(u32*)(lo + (size_t)n * C + c0 + (ty << 2)) = pl;
    }
  } else {
    ush* gp = (ush*)(wsu8 + OFF_G) + (size_t)b * C * N;
#pragma unroll
    for (int i = 0; i < 4; ++i) {
      ushort4 pk;
      pk.x = f2bf(acc[i][0]); pk.y = f2bf(acc[i][1]);
      pk.z = f2bf(acc[i][2]); pk.w = f2bf(acc[i][3]);
      *reinterpret_cast<ushort4*>(&gp[(size_t)(c0 + (ty << 2) + i) * N + nb + (tx << 2)]) = pk;
    }
  }
}

// ---------------- kernel 2: column-softmax stats, counted-vmcnt pipeline ----
// grid (32 mt, 4 chunk, 4 b) = 512 blocks, 512 thr = 8 waves (wr2 x wc4).
// LDS: resident phi hi/lo [0,64K); theta k-half buffers T0/T1/T2 (3x16K).
// Per nt: 2 phases (k-halves). Stage distance 2 phases; steady wait vmcnt(2).
__global__ __launch_bounds__(512, 1) void stats_kernel(
    const char* __restrict__ wsu8, float* __restrict__ fws) {
  __shared__ __align__(16) char lds[114688];
  const int tid = threadIdx.x, lane = tid & 63, w = tid >> 6;
  const int l31 = lane & 31, lh5 = lane >> 5;
  const int wr = w >> 2, wc = w & 3;
  int flat = (blockIdx.z * NCH + blockIdx.y) * 32 + blockIdx.x;
  int nf = ((flat & 7) << 6) | (flat >> 3);   // XCD swizzle (512 = 8*64)
  const int b = nf >> 7, rem = nf & 127, chunk = rem >> 5, mt = rem & 31;
  const int mb = mt * 128, cbase = chunk * 1024;
  const size_t bo = (size_t)b * N * C;
  const char* th  = wsu8 + OFF_TH + bo;
  const char* tl  = wsu8 + OFF_TL + bo;
  const char* ph  = wsu8 + OFF_PH + bo;
  const char* plo = wsu8 + OFF_PLO + bo;

  // resident phi [128m][256k] hi+lo (64KB) into lds[0,64K)
#pragma unroll
  for (int cix = 0; cix < 8; ++cix) {
    int plane = cix >> 2, q = cix & 3;
    int rl = q * 32 + w * 4 + (lane >> 4);
    int gc = lane & 15;
    const char* src = (plane ? plo : ph) + (size_t)(mb + rl) * C + ((gc ^ (rl & 15)) << 4);
    gload16(src, lds + plane * 32768 + q * 8192 + w * 1024 + lane * 16);
  }
  char* const T0 = lds + 65536;
  char* const T1 = lds + 65536 + 16384;
  char* const T2 = lds + 65536 + 32768;

  // stage s: theta k-half (s&1) of n-tile (s>>1): [64 rows][128 k-bytes] x2 planes
  auto stage = [&](int s, char* dst) {
    int ntx = s >> 1, h = s & 1;
    int rl = w * 8 + (lane >> 3);
    int gc = lane & 7;
#pragma unroll
    for (int plane = 0; plane < 2; ++plane) {
      const char* src = (plane ? tl : th) +
          (size_t)(cbase + ntx * 64 + rl) * C + h * 128 + ((gc ^ (rl & 7)) << 4);
      gload16(src, dst + plane * 8192 + w * 1024 + lane * 16);
    }
  };

  stage(0, T0); stage(1, T1);
  WAITV(2);            // resident phi + stage0 done; stage1 may be in flight
  PBAR;

  const int m = mb + wc * 32 + l31;   // this lane's column
  const int mcl = m & 63, mh = m >> 6;
  const int arow = wr * 32 + l31;
  const int brow = wc * 32 + l31;
  const int aswz = arow & 7, bswz = brow & 15;
  const int nbl = wr * 32;
  float rmax = -3e38f, rsum = 0.0f;

  char* Tc = T0; char* Tn = T1; char* Tn2 = T2;
  for (int nt = 0; nt < 16; ++nt) {
    i32x16 HH = {}, XX = {};
#pragma unroll
    for (int h = 0; h < 2; ++h) {
      int p = nt * 2 + h;
      if (p + 2 < 32) stage(p + 2, Tn2);
      __builtin_amdgcn_s_setprio(1);
#pragma unroll
      for (int kt = 0; kt < 4; ++kt) {
        int ga = (((kt * 2 + lh5) ^ aswz) << 4);
        i32x4 ah = *(const i32x4*)(Tc + arow * 128 + ga);
        i32x4 al = *(const i32x4*)(Tc + 8192 + arow * 128 + ga);
        int g = h * 4 + kt;
        int gb = (((g * 2 + lh5) ^ bswz) << 4);
        i32x4 bh = *(const i32x4*)(lds + brow * 256 + gb);
        i32x4 bl = *(const i32x4*)(lds + 32768 + brow * 256 + gb);
        HH = MFMAI8(ah, bh, HH);
        XX = MFMAI8(ah, bl, XX);
        XX = MFMAI8(al, bh, XX);
      }
      __builtin_amdgcn_s_setprio(0);
      if (h == 1) {
        int dyi = (cbase >> 6) + nt - mh;      // n>>6 - m>>6, const per nt
        float dy2 = (float)(dyi * dyi);
#pragma unroll
        for (int r = 0; r < 16; ++r) {
          int pr = (r & 3) + 8 * (r >> 2) + 4 * lh5;
          float bs = score_l2(HH[r], XX[r], nbl + pr - mcl, dy2);
          float nm = fmaxf(rmax, bs);
          rsum = rsum * exp2f(rmax - nm) + exp2f(bs - nm);
          rmax = nm;
        }
      }
      if (p + 2 < 32) { WAITV(2); } else { WAITV(0); }
      PBAR;
      char* t = Tc; Tc = Tn; Tn = Tn2; Tn2 = t;
    }
  }
  // lanes l and l^32 share a column
  {
    float om = __shfl_xor(rmax, 32);
    float os = __shfl_xor(rsum, 32);
    float nm = fmaxf(rmax, om);
    rsum = rsum * exp2f(rmax - nm) + os * exp2f(om - nm);
    rmax = nm;
  }
  float* redM = (float*)lds;            // [2][128]
  float* redS = (float*)(lds + 1024);
  if (lane < 32) {
    redM[wr * 128 + wc * 32 + l31] = rmax;
    redS[wr * 128 + wc * 32 + l31] = rsum;
  }
  __syncthreads();
  if (tid < 128) {
    float m0 = redM[tid], m1 = redM[128 + tid];
    float nm = fmaxf(m0, m1);
    float s = redS[tid] * exp2f(m0 - nm) + redS[128 + tid] * exp2f(m1 - nm);
    fws[F_PM + ((size_t)(b * NCH + chunk)) * N + mb + tid] = nm;
    fws[F_PS + ((size_t)(b * NCH + chunk)) * N + mb + tid] = s;
  }
}

// ---------------- kernel 3: reduce partial stats -> Q[m] = max + log2(sum) --
__global__ __launch_bounds__(256) void finalize_stats(float* __restrict__ fws) {
  int id = blockIdx.x * 256 + threadIdx.x;
  if (id >= B * N) return;
  int b = id >> 12, m = id & (N - 1);
  float M = -3e38f;
#pragma unroll
  for (int ch = 0; ch < NCH; ++ch)
    M = fmaxf(M, fws[F_PM + (size_t)(b * NCH + ch) * N + m]);
  float S = 0.0f;
#pragma unroll
  for (int ch = 0; ch < NCH; ++ch)
    S += fws[F_PS + (size_t)(b * NCH + ch) * N + m] *
         exp2f(fws[F_PM + (size_t)(b * NCH + ch) * N + m] - M);
  fws[F_M + id] = M + __log2f(S);   // single fused constant Q[m]
}

// ---------------- kernel 4: scores + softmax + PV, counted-vmcnt pipeline ---
// grid (64 ntile, B) = 256 blocks, 512 thr = 8 waves. n-tile 64, mc m-tile 128.
// Resident theta (A operand) in registers (TH/TL). Q pre-staged in LDS.
// LDS: R0/R1/R2 staging (3x32K), Pb[96K,112K), Qb[112K,128K).
// Stage stream per mc: {G0, G1, phiK0(mc+1), phiK1(mc+1)}, distance 2 phases,
// steady wait vmcnt(4) (one 4-load stage in flight across each barrier).
__global__ __launch_bounds__(512, 1) void out_kernel(
    const float* __restrict__ x, float* __restrict__ out,
    const char* __restrict__ wsu8, const float* __restrict__ fws) {
  __shared__ __align__(16) char lds[131072];
  const int tid = threadIdx.x, lane = tid & 63, w = tid >> 6;
  const int l31 = lane & 31, lh5 = lane >> 5;
  const int wn = w >> 2, wm = w & 3;   // score wave tile: [wn*32 n][wm*32 m]
  int flat = blockIdx.y * gridDim.x + blockIdx.x;
  int nf = ((flat & 7) << 5) | (flat >> 3);   // XCD swizzle (256 = 8*32)
  const int b = nf >> 6, ntile = nf & 63;
  const int n0 = ntile * 64;
  const size_t bo = (size_t)b * N * C;
  const char* th  = wsu8 + OFF_TH + bo;
  const char* tl  = wsu8 + OFF_TL + bo;
  const char* ph  = wsu8 + OFF_PH + bo;
  const char* plo = wsu8 + OFF_PLO + bo;
  const char* GPB = wsu8 + OFF_G + (size_t)b * C * N * 2;  // bf16 [C][N] bytes
  const float* Qv = fws + F_M + (size_t)b * N;

  char* const R0 = lds;
  char* const R1 = lds + 32768;
  char* const R2 = lds + 65536;
  char* const Pb = lds + 98304;
  char* const Qb = lds + 114688;

  const int arow = wn * 32 + l31;            // theta row (n-local)
  const int brow = wm * 32 + l31;            // phi row (m-local)
  const int grow = w * 32 + l31;             // G row (c)
  const int bswz = brow & 7, gswz = grow & 7;

  // resident theta fragments (A operand) -> registers, once
  i32x4 TH[8], TL[8];
  {
    const char* trh = th + (size_t)(n0 + arow) * C + lh5 * 16;
    const char* trl = tl + (size_t)(n0 + arow) * C + lh5 * 16;
#pragma unroll
    for (int q = 0; q < 8; ++q) {
      TH[q] = *(const i32x4*)(trh + q * 32);
      TL[q] = *(const i32x4*)(trl + q * 32);
    }
  }
  // Q[4096] f32 -> LDS (16KB), keeps in-loop vmem = staging only
#pragma unroll
  for (int i = 0; i < 2; ++i)
    gload16((const char*)Qv + i * 8192 + w * 1024 + lane * 16,
            Qb + i * 8192 + w * 1024 + lane * 16);

  auto stagePhi = [&](int mrow0, int khalf, char* dst) {
#pragma unroll
    for (int cix = 0; cix < 4; ++cix) {
      int plane = cix >> 1, q = cix & 1;
      int rl = q * 64 + w * 8 + (lane >> 3);
      int gc = lane & 7;
      const char* src = (plane ? plo : ph) +
          (size_t)(mrow0 + rl) * C + khalf * 128 + ((gc ^ (rl & 7)) << 4);
      gload16(src, dst + plane * 16384 + q * 8192 + w * 1024 + lane * 16);
    }
  };
  auto stageG = [&](int m0g, char* dst) {
#pragma unroll
    for (int cix = 0; cix < 4; ++cix) {
      int rl = cix * 64 + w * 8 + (lane >> 3);
      int gc = lane & 7;
      const char* src = GPB + (size_t)rl * (N * 2) + (size_t)m0g * 2 + ((gc ^ (rl & 7)) << 4);
      gload16(src, dst + cix * 8192 + w * 1024 + lane * 16);
    }
  };

  // prologue: phiK0(0)->R0, phiK1(0)->R1
  stagePhi(0, 0, R0);
  stagePhi(0, 1, R1);
  WAITV(4);            // TH/TL, Qb, phiK0 done; phiK1 may be in flight
  PBAR;

  f32x16 oacc0 = {}, oacc1 = {};
  char* Bc = R0; char* Bn = R1; char* Bn2 = R2;

  for (int mc = 0; mc < 32; ++mc) {
    const int m0 = mc * 128;
    i32x16 HH = {}, XX = {};
    const int mg = m0 + wm * 32 + l31;
    const float Qm = *(const float*)(Qb + 4 * mg);
    const int mcl = mg & 63;

    // ---- phase A: issue G0(mc)->Bn2; scoreK0 from Bc (phiK0)
    stageG(m0, Bn2);
    __builtin_amdgcn_s_setprio(1);
#pragma unroll
    for (int kt = 0; kt < 4; ++kt) {
      int gb = (((kt * 2 + lh5) ^ bswz) << 4);
      i32x4 bh = *(const i32x4*)(Bc + brow * 128 + gb);
      i32x4 bl = *(const i32x4*)(Bc + 16384 + brow * 128 + gb);
      HH = MFMAI8(TH[kt], bh, HH);
      XX = MFMAI8(TH[kt], bl, XX);
      XX = MFMAI8(TL[kt], bh, XX);
    }
    __builtin_amdgcn_s_setprio(0);
    WAITV(4); PBAR;

    // ---- phase B: issue G1(mc)->Bc; scoreK1 from Bn (phiK1); softmax -> Pb
    stageG(m0 + 64, Bc);
    __builtin_amdgcn_s_setprio(1);
#pragma unroll
    for (int kt = 0; kt < 4; ++kt) {
      int gb = (((kt * 2 + lh5) ^ bswz) << 4);
      i32x4 bh = *(const i32x4*)(Bn + brow * 128 + gb);
      i32x4 bl = *(const i32x4*)(Bn + 16384 + brow * 128 + gb);
      HH = MFMAI8(TH[4 + kt], bh, HH);
      XX = MFMAI8(TH[4 + kt], bl, XX);
      XX = MFMAI8(TL[4 + kt], bh, XX);
    }
    __builtin_amdgcn_s_setprio(0);
    {
      const int pcol = wm * 32 + l31;
      const int gP = pcol >> 3, bP = (pcol & 7) << 1;
      int dyi = ntile - (mg >> 6);
      float dy2 = (float)(dyi * dyi);
#pragma unroll
      for (int r = 0; r < 16; ++r) {
        int prow = wn * 32 + (r & 3) + 8 * (r >> 2) + 4 * lh5;
        float bs = score_l2(HH[r], XX[r], prow - mcl, dy2);
        float pv = exp2f(bs - Qm);
        *(ush*)(Pb + prow * 256 + (((gP ^ (prow & 15)) << 4)) + bP) = f2bf(pv);
      }
    }
    WAITVL(4); PBAR;   // G0 done; P visible

    // ---- phase C: issue phiK0(mc+1)->Bn; PV half 0 from Bn2 (G0)
    if (mc < 31) stagePhi(m0 + 128, 0, Bn);
    __builtin_amdgcn_s_setprio(1);
#pragma unroll
    for (int t2 = 0; t2 < 4; ++t2) {
      int gG = (((t2 * 2 + lh5) ^ gswz) << 4);
      short8 gb = *(const short8*)(Bn2 + grow * 128 + gG);
      {
        int gP0 = ((((t2 * 2 + lh5) ^ (l31 & 15)) << 4));
        short8 pa = *(const short8*)(Pb + l31 * 256 + gP0);
        oacc0 = MFMABF(pa, gb, oacc0);
      }
      {
        int ar = 32 + l31;
        int gP1 = ((((t2 * 2 + lh5) ^ (ar & 15)) << 4));
        short8 pa = *(const short8*)(Pb + ar * 256 + gP1);
        oacc1 = MFMABF(pa, gb, oacc1);
      }
    }
    __builtin_amdgcn_s_setprio(0);
    if (mc < 31) { WAITV(4); } else { WAITV(0); }
    PBAR;

    // ---- phase D: issue phiK1(mc+1)->Bn2; PV half 1 from Bc (G1)
    if (mc < 31) stagePhi(m0 + 128, 1, Bn2);
    __builtin_amdgcn_s_setprio(1);
#pragma unroll
    for (int t2 = 0; t2 < 4; ++t2) {
      int gG = (((t2 * 2 + lh5) ^ gswz) << 4);
      short8 gb = *(const short8*)(Bc + grow * 128 + gG);
      {
        int gP0 = ((((8 + t2 * 2 + lh5) ^ (l31 & 15)) << 4));
        short8 pa = *(const short8*)(Pb + l31 * 256 + gP0);
        oacc0 = MFMABF(pa, gb, oacc0);
      }
      {
        int ar = 32 + l31;
        int gP1 = ((((8 + t2 * 2 + lh5) ^ (ar & 15)) << 4));
        short8 pa = *(const short8*)(Pb + ar * 256 + gP1);
        oacc1 = MFMABF(pa, gb, oacc1);
      }
    }
    __builtin_amdgcn_s_setprio(0);
    if (mc < 31) { WAITV(4); } else { WAITV(0); }
    PBAR;

    char* t = Bc; Bc = Bn; Bn = Bn2; Bn2 = t;
  }

  // epilogue: transpose [n][c] -> [c][n] via LDS, residual, store
  float* Tr = (float*)lds;   // [256 c][65]
  const int c = w * 32 + l31;
#pragma unroll
  for (int r = 0; r < 16; ++r) {
    int crow = (r & 3) + 8 * (r >> 2) + 4 * lh5;
    Tr[c * 65 + crow] = oacc0[r];
    Tr[c * 65 + 32 + crow] = oacc1[r];
  }
  __syncthreads();
  const float* xb = x + (size_t)b * C * N;
  float* ob = out + (size_t)b * C * N;
  for (int e = tid; e < 16384; e += 512) {
    int cc = e >> 6, nl = e & 63;
    size_t idx = (size_t)cc * N + n0 + nl;
    ob[idx] = Tr[cc * 65 + nl] + xb[idx];
  }
}

extern "C" void kernel_launch(void* const* d_in, const int* in_sizes, int n_in,
                              void* d_out, int out_size, void* d_ws, size_t ws_size,
                              hipStream_t stream) {
  const float* x       = (const float*)d_in[0];
  const float* w_phi   = (const float*)d_in[1];
  const float* w_theta = (const float*)d_in[2];
  const float* w_g     = (const float*)d_in[3];
  float* out = (float*)d_out;
  char* wsu8 = (char*)d_ws;                      // ~24.3 MB used
  float* fws = (float*)(wsu8 + FOFF);

  proj_kernel<<<dim3(256, 12), 256, 0, stream>>>(x, w_phi, w_theta, w_g, wsu8);
  stats_kernel<<<dim3(32, NCH, B), 512, 0, stream>>>(wsu8, fws);
  finalize_stats<<<dim3(B * N / 256), 256, 0, stream>>>(fws);
  out_kernel<<<dim3(64, B), 512, 0, stream>>>(x, out, wsu8, fws);
}

// Round 4
// 257.298 us; speedup vs baseline: 1.2650x; 1.2650x over previous
//
#include <hip/hip_runtime.h>
#include <math.h>

typedef unsigned short ush;
typedef short short8 __attribute__((ext_vector_type(8)));
typedef int i32x4 __attribute__((ext_vector_type(4)));
typedef int i32x16 __attribute__((ext_vector_type(16)));
typedef float f32x16 __attribute__((ext_vector_type(16)));
typedef unsigned int u32;

namespace {
constexpr int B = 4, C = 256, N = 4096, NCH = 4;
constexpr size_t PL8 = (size_t)B * N * C;              // 4 MB
constexpr size_t OFF_TH  = 0;
constexpr size_t OFF_TL  = PL8;
constexpr size_t OFF_PH  = 2 * PL8;
constexpr size_t OFF_PLO = 3 * PL8;
constexpr size_t OFF_G   = 4 * PL8;                    // bf16 [B][C][N], 8 MB
constexpr size_t FOFF    = 4 * PL8 + (size_t)B * C * N * 2;  // 24 MB
constexpr size_t F_PM = 0;
constexpr size_t F_PS = (size_t)B * NCH * N;
constexpr size_t F_M  = 2 * (size_t)B * NCH * N;

constexpr float SCL = 8.0f / 127.0f;
constexpr float S2  = SCL * SCL;
constexpr float RB  = 1.5f / 89.09545f;
constexpr float L2E = 1.44269504f;                     // log2(e)
constexpr float BA2  = 2.0f * S2 * L2E;                // bias consts pre-scaled by log2e
constexpr float BBC2 = RB * S2 * L2E;
constexpr float C1  = 1.0f / 254.0f;
constexpr float INV_SCL = 127.0f / 8.0f;
}

#define MFMAI8(a, b, c)  __builtin_amdgcn_mfma_i32_32x32x32_i8((a), (b), (c), 0, 0, 0)
#define MFMABF(a, b, c)  __builtin_amdgcn_mfma_f32_32x32x16_bf16((a), (b), (c), 0, 0, 0)

// counted-vmcnt pipeline barriers (T3+T4): never drain to 0 in steady state
#define WAITV(n) asm volatile("s_waitcnt vmcnt(" #n ")" ::: "memory")
#define WAITVL(n) asm volatile("s_waitcnt vmcnt(" #n ") lgkmcnt(0)" ::: "memory")
#define PBAR __builtin_amdgcn_s_barrier()

__device__ __forceinline__ float fast_exp2(float x) {
#if __has_builtin(__builtin_amdgcn_exp2f)
  return __builtin_amdgcn_exp2f(x);
#else
  float r; asm("v_exp_f32 %0, %1" : "=v"(r) : "v"(x)); return r;
#endif
}
__device__ __forceinline__ float fast_sqrt(float x) {
#if __has_builtin(__builtin_amdgcn_sqrtf)
  return __builtin_amdgcn_sqrtf(x);
#else
  float r; asm("v_sqrt_f32 %0, %1" : "=v"(r) : "v"(x)); return r;
#endif
}

__device__ __forceinline__ ush f2bf(float v) {
  u32 x = __float_as_uint(v);
  return (ush)((x + 0x7FFFu + ((x >> 16) & 1u)) >> 16);
}

// shared by stats & out: MUST produce bit-identical results in both kernels
// (i32 inputs exact; d2 = dx^2+dy^2 is an exact small integer in both).
// Returns the biased score in log2 domain (log2e folded into BA2/BBC2).
__device__ __forceinline__ float score_d2(int hh, int xx, float d2) {
  float u = fmaf((float)xx, C1, (float)hh);
  float d = fast_sqrt(d2);
  return fmaf(d, -BBC2, BA2) * u;
}

__device__ __forceinline__ void gload16(const void* g, void* l) {
  __builtin_amdgcn_global_load_lds(
      (const __attribute__((address_space(1))) u32*)(g),
      (__attribute__((address_space(3))) u32*)(l), 16, 0, 0);
}

// ---------------- kernel 1: projections -> i8 hi/lo planes + bf16 g --------
__global__ __launch_bounds__(256) void proj_kernel(
    const float* __restrict__ x, const float* __restrict__ w_phi,
    const float* __restrict__ w_theta, const float* __restrict__ w_g,
    char* __restrict__ wsu8) {
  __shared__ float Wst[16][68];
  __shared__ float Xs[16][68];
  const int tid = threadIdx.x, tx = tid & 15, ty = tid >> 4;
  const int b = blockIdx.y / 3, p = blockIdx.y % 3;
  const int c0 = (blockIdx.x >> 6) * 64;
  const int nb = (blockIdx.x & 63) * 64;
  const float* w = (p == 0) ? w_theta : (p == 1) ? w_phi : w_g;

  float acc[4][4] = {};
  for (int kk = 0; kk < C; kk += 16) {
    {
      int r = tid >> 2, kq = (tid & 3) << 2;
      float4 v = *reinterpret_cast<const float4*>(&w[(size_t)(c0 + r) * C + kk + kq]);
      Wst[kq + 0][r] = v.x; Wst[kq + 1][r] = v.y;
      Wst[kq + 2][r] = v.z; Wst[kq + 3][r] = v.w;
    }
    {
      int k = tid >> 4, j4 = (tid & 15) << 2;
      *reinterpret_cast<float4*>(&Xs[k][j4]) =
          *reinterpret_cast<const float4*>(&x[((size_t)b * C + kk + k) * N + nb + j4]);
    }
    __syncthreads();
#pragma unroll
    for (int k2 = 0; k2 < 16; ++k2) {
      float4 av = *reinterpret_cast<const float4*>(&Wst[k2][ty << 2]);
      float4 bv = *reinterpret_cast<const float4*>(&Xs[k2][tx << 2]);
      float aa[4] = {av.x, av.y, av.z, av.w};
      float bb[4] = {bv.x, bv.y, bv.z, bv.w};
#pragma unroll
      for (int i = 0; i < 4; ++i)
#pragma unroll
        for (int j = 0; j < 4; ++j) acc[i][j] = fmaf(aa[i], bb[j], acc[i][j]);
    }
    __syncthreads();
  }

  if (p < 2) {
    char* hi = wsu8 + (p == 0 ? OFF_TH : OFF_PH) + (size_t)b * N * C;
    char* lo = wsu8 + (p == 0 ? OFF_TL : OFF_PLO) + (size_t)b * N * C;
#pragma unroll
    for (int j = 0; j < 4; ++j) {
      int n = nb + (tx << 2) + j;
      u32 ph = 0, pl = 0;
#pragma unroll
      for (int i = 0; i < 4; ++i) {
        float t = acc[i][j] * INV_SCL;
        int h = __float2int_rn(t);
        h = max(-127, min(127, h));
        int l = __float2int_rn((t - (float)h) * 254.0f);
        l = max(-127, min(127, l));
        ph |= ((u32)(h & 0xFF)) << (8 * i);
        pl |= ((u32)(l & 0xFF)) << (8 * i);
      }
      *(u32*)(hi + (size_t)n * C + c0 + (ty << 2)) = ph;
      *(u32*)(lo + (size_t)n * C + c0 + (ty << 2)) = pl;
    }
  } else {
    ush* gp = (ush*)(wsu8 + OFF_G) + (size_t)b * C * N;
#pragma unroll
    for (int i = 0; i < 4; ++i) {
      ushort4 pk;
      pk.x = f2bf(acc[i][0]); pk.y = f2bf(acc[i][1]);
      pk.z = f2bf(acc[i][2]); pk.w = f2bf(acc[i][3]);
      *reinterpret_cast<ushort4*>(&gp[(size_t)(c0 + (ty << 2) + i) * N + nb + (tx << 2)]) = pk;
    }
  }
}

// ---------------- kernel 2: column-softmax stats, counted-vmcnt pipeline ----
// grid (32 mt, 4 chunk, 4 b) = 512 blocks, 512 thr = 8 waves (wr2 x wc4).
// LDS: resident phi hi/lo [0,64K); theta k-half buffers T0/T1/T2 (3x16K).
// Per nt: 2 phases (k-halves). Stage distance 2 phases; steady wait vmcnt(2).
__global__ __launch_bounds__(512, 1) void stats_kernel(
    const char* __restrict__ wsu8, float* __restrict__ fws) {
  __shared__ __align__(16) char lds[114688];
  const int tid = threadIdx.x, lane = tid & 63, w = tid >> 6;
  const int l31 = lane & 31, lh5 = lane >> 5;
  const int wr = w >> 2, wc = w & 3;
  int flat = (blockIdx.z * NCH + blockIdx.y) * 32 + blockIdx.x;
  int nf = ((flat & 7) << 6) | (flat >> 3);   // XCD swizzle (512 = 8*64)
  const int b = nf >> 7, rem = nf & 127, chunk = rem >> 5, mt = rem & 31;
  const int mb = mt * 128, cbase = chunk * 1024;
  const size_t bo = (size_t)b * N * C;
  const char* th  = wsu8 + OFF_TH + bo;
  const char* tl  = wsu8 + OFF_TL + bo;
  const char* ph  = wsu8 + OFF_PH + bo;
  const char* plo = wsu8 + OFF_PLO + bo;

  // resident phi [128m][256k] hi+lo (64KB) into lds[0,64K)
#pragma unroll
  for (int cix = 0; cix < 8; ++cix) {
    int plane = cix >> 2, q = cix & 3;
    int rl = q * 32 + w * 4 + (lane >> 4);
    int gc = lane & 15;
    const char* src = (plane ? plo : ph) + (size_t)(mb + rl) * C + ((gc ^ (rl & 15)) << 4);
    gload16(src, lds + plane * 32768 + q * 8192 + w * 1024 + lane * 16);
  }
  char* const T0 = lds + 65536;
  char* const T1 = lds + 65536 + 16384;
  char* const T2 = lds + 65536 + 32768;

  // stage s: theta k-half (s&1) of n-tile (s>>1): [64 rows][128 k-bytes] x2 planes
  auto stage = [&](int s, char* dst) {
    int ntx = s >> 1, h = s & 1;
    int rl = w * 8 + (lane >> 3);
    int gc = lane & 7;
#pragma unroll
    for (int plane = 0; plane < 2; ++plane) {
      const char* src = (plane ? tl : th) +
          (size_t)(cbase + ntx * 64 + rl) * C + h * 128 + ((gc ^ (rl & 7)) << 4);
      gload16(src, dst + plane * 8192 + w * 1024 + lane * 16);
    }
  };

  stage(0, T0); stage(1, T1);
  WAITV(2);            // resident phi + stage0 done; stage1 may be in flight
  PBAR;

  const int m = mb + wc * 32 + l31;   // this lane's column
  const int mcl = m & 63, mh = m >> 6;
  const int arow = wr * 32 + l31;
  const int brow = wc * 32 + l31;
  const int aswz = arow & 7, bswz = brow & 15;
  const int nbl = wr * 32;
  float rmax = -3e38f, rsum = 0.0f;

  // dx^2 table: constant across nt (mb multiple of 64 -> mcl const)
  float dx2f[16];
#pragma unroll
  for (int r = 0; r < 16; ++r) {
    int pr = (r & 3) + 8 * (r >> 2) + 4 * lh5;
    int dxi = nbl + pr - mcl;
    dx2f[r] = (float)(dxi * dxi);
  }

  char* Tc = T0; char* Tn = T1; char* Tn2 = T2;
  for (int nt = 0; nt < 16; ++nt) {
    i32x16 HH = {}, XX = {};
#pragma unroll
    for (int h = 0; h < 2; ++h) {
      int p = nt * 2 + h;
      if (p + 2 < 32) stage(p + 2, Tn2);
      __builtin_amdgcn_s_setprio(1);
#pragma unroll
      for (int kt = 0; kt < 4; ++kt) {
        int ga = (((kt * 2 + lh5) ^ aswz) << 4);
        i32x4 ah = *(const i32x4*)(Tc + arow * 128 + ga);
        i32x4 al = *(const i32x4*)(Tc + 8192 + arow * 128 + ga);
        int g = h * 4 + kt;
        int gb = (((g * 2 + lh5) ^ bswz) << 4);
        i32x4 bh = *(const i32x4*)(lds + brow * 256 + gb);
        i32x4 bl = *(const i32x4*)(lds + 32768 + brow * 256 + gb);
        HH = MFMAI8(ah, bh, HH);
        XX = MFMAI8(ah, bl, XX);
        XX = MFMAI8(al, bh, XX);
      }
      __builtin_amdgcn_s_setprio(0);
      if (h == 1) {
        int dyi = (cbase >> 6) + nt - mh;      // n>>6 - m>>6, const per nt
        float dy2 = (float)(dyi * dyi);
        float bs[16];
#pragma unroll
        for (int r = 0; r < 16; ++r)
          bs[r] = score_d2(HH[r], XX[r], dx2f[r] + dy2);
        float m0 = fmaxf(fmaxf(fmaxf(bs[0], bs[1]), fmaxf(bs[2], bs[3])),
                         fmaxf(fmaxf(bs[4], bs[5]), fmaxf(bs[6], bs[7])));
        float m1 = fmaxf(fmaxf(fmaxf(bs[8], bs[9]), fmaxf(bs[10], bs[11])),
                         fmaxf(fmaxf(bs[12], bs[13]), fmaxf(bs[14], bs[15])));
        float nm = fmaxf(rmax, fmaxf(m0, m1));
        float e[16];
#pragma unroll
        for (int r = 0; r < 16; ++r) e[r] = fast_exp2(bs[r] - nm);
        float s0 = ((e[0] + e[1]) + (e[2] + e[3])) + ((e[4] + e[5]) + (e[6] + e[7]));
        float s1 = ((e[8] + e[9]) + (e[10] + e[11])) + ((e[12] + e[13]) + (e[14] + e[15]));
        rsum = fmaf(rsum, fast_exp2(rmax - nm), s0 + s1);
        rmax = nm;
      }
      if (p + 2 < 32) { WAITV(2); } else { WAITV(0); }
      PBAR;
      char* t = Tc; Tc = Tn; Tn = Tn2; Tn2 = t;
    }
  }
  // lanes l and l^32 share a column
  {
    float om = __shfl_xor(rmax, 32);
    float os = __shfl_xor(rsum, 32);
    float nm = fmaxf(rmax, om);
    rsum = rsum * fast_exp2(rmax - nm) + os * fast_exp2(om - nm);
    rmax = nm;
  }
  float* redM = (float*)lds;            // [2][128]
  float* redS = (float*)(lds + 1024);
  if (lane < 32) {
    redM[wr * 128 + wc * 32 + l31] = rmax;
    redS[wr * 128 + wc * 32 + l31] = rsum;
  }
  __syncthreads();
  if (tid < 128) {
    float m0 = redM[tid], m1 = redM[128 + tid];
    float nm = fmaxf(m0, m1);
    float s = redS[tid] * fast_exp2(m0 - nm) + redS[128 + tid] * fast_exp2(m1 - nm);
    fws[F_PM + ((size_t)(b * NCH + chunk)) * N + mb + tid] = nm;
    fws[F_PS + ((size_t)(b * NCH + chunk)) * N + mb + tid] = s;
  }
}

// ---------------- kernel 3: reduce partial stats -> Q[m] = max + log2(sum) --
__global__ __launch_bounds__(256) void finalize_stats(float* __restrict__ fws) {
  int id = blockIdx.x * 256 + threadIdx.x;
  if (id >= B * N) return;
  int b = id >> 12, m = id & (N - 1);
  float M = -3e38f;
#pragma unroll
  for (int ch = 0; ch < NCH; ++ch)
    M = fmaxf(M, fws[F_PM + (size_t)(b * NCH + ch) * N + m]);
  float S = 0.0f;
#pragma unroll
  for (int ch = 0; ch < NCH; ++ch)
    S += fws[F_PS + (size_t)(b * NCH + ch) * N + m] *
         fast_exp2(fws[F_PM + (size_t)(b * NCH + ch) * N + m] - M);
  fws[F_M + id] = M + __log2f(S);   // single fused constant Q[m]
}

// ---------------- kernel 4: scores + softmax + PV, counted-vmcnt pipeline ---
// grid (64 ntile, B) = 256 blocks, 512 thr = 8 waves. n-tile 64, mc m-tile 128.
// Resident theta (A operand) in registers (TH/TL). Q pre-staged in LDS.
// LDS: R0/R1/R2 staging (3x32K), Pb[96K,112K), Qb[112K,128K).
// Stage stream per mc: {G0, G1, phiK0(mc+1), phiK1(mc+1)}, distance 2 phases,
// steady wait vmcnt(4) (one 4-load stage in flight across each barrier).
__global__ __launch_bounds__(512, 1) void out_kernel(
    const float* __restrict__ x, float* __restrict__ out,
    const char* __restrict__ wsu8, const float* __restrict__ fws) {
  __shared__ __align__(16) char lds[131072];
  const int tid = threadIdx.x, lane = tid & 63, w = tid >> 6;
  const int l31 = lane & 31, lh5 = lane >> 5;
  const int wn = w >> 2, wm = w & 3;   // score wave tile: [wn*32 n][wm*32 m]
  int flat = blockIdx.y * gridDim.x + blockIdx.x;
  int nf = ((flat & 7) << 5) | (flat >> 3);   // XCD swizzle (256 = 8*32)
  const int b = nf >> 6, ntile = nf & 63;
  const int n0 = ntile * 64;
  const size_t bo = (size_t)b * N * C;
  const char* th  = wsu8 + OFF_TH + bo;
  const char* tl  = wsu8 + OFF_TL + bo;
  const char* ph  = wsu8 + OFF_PH + bo;
  const char* plo = wsu8 + OFF_PLO + bo;
  const char* GPB = wsu8 + OFF_G + (size_t)b * C * N * 2;  // bf16 [C][N] bytes
  const float* Qv = fws + F_M + (size_t)b * N;

  char* const R0 = lds;
  char* const R1 = lds + 32768;
  char* const R2 = lds + 65536;
  char* const Pb = lds + 98304;
  char* const Qb = lds + 114688;

  const int arow = wn * 32 + l31;            // theta row (n-local)
  const int brow = wm * 32 + l31;            // phi row (m-local)
  const int grow = w * 32 + l31;             // G row (c)
  const int bswz = brow & 7, gswz = grow & 7;
  const int mcl = (wm * 32 + l31) & 63;      // m&63: const across mc (stride 128)

  // resident theta fragments (A operand) -> registers, once
  i32x4 TH[8], TL[8];
  {
    const char* trh = th + (size_t)(n0 + arow) * C + lh5 * 16;
    const char* trl = tl + (size_t)(n0 + arow) * C + lh5 * 16;
#pragma unroll
    for (int q = 0; q < 8; ++q) {
      TH[q] = *(const i32x4*)(trh + q * 32);
      TL[q] = *(const i32x4*)(trl + q * 32);
    }
  }
  // dx^2 table: constant across mc
  float dx2f[16];
#pragma unroll
  for (int r = 0; r < 16; ++r) {
    int prow = wn * 32 + (r & 3) + 8 * (r >> 2) + 4 * lh5;
    int dxi = prow - mcl;
    dx2f[r] = (float)(dxi * dxi);
  }
  // Q[4096] f32 -> LDS (16KB), keeps in-loop vmem = staging only
#pragma unroll
  for (int i = 0; i < 2; ++i)
    gload16((const char*)Qv + i * 8192 + w * 1024 + lane * 16,
            Qb + i * 8192 + w * 1024 + lane * 16);

  auto stagePhi = [&](int mrow0, int khalf, char* dst) {
#pragma unroll
    for (int cix = 0; cix < 4; ++cix) {
      int plane = cix >> 1, q = cix & 1;
      int rl = q * 64 + w * 8 + (lane >> 3);
      int gc = lane & 7;
      const char* src = (plane ? plo : ph) +
          (size_t)(mrow0 + rl) * C + khalf * 128 + ((gc ^ (rl & 7)) << 4);
      gload16(src, dst + plane * 16384 + q * 8192 + w * 1024 + lane * 16);
    }
  };
  auto stageG = [&](int m0g, char* dst) {
#pragma unroll
    for (int cix = 0; cix < 4; ++cix) {
      int rl = cix * 64 + w * 8 + (lane >> 3);
      int gc = lane & 7;
      const char* src = GPB + (size_t)rl * (N * 2) + (size_t)m0g * 2 + ((gc ^ (rl & 7)) << 4);
      gload16(src, dst + cix * 8192 + w * 1024 + lane * 16);
    }
  };

  // prologue: phiK0(0)->R0, phiK1(0)->R1
  stagePhi(0, 0, R0);
  stagePhi(0, 1, R1);
  WAITV(4);            // TH/TL, Qb, phiK0 done; phiK1 may be in flight
  PBAR;

  f32x16 oacc0 = {}, oacc1 = {};
  char* Bc = R0; char* Bn = R1; char* Bn2 = R2;

  for (int mc = 0; mc < 32; ++mc) {
    const int m0 = mc * 128;
    i32x16 HH = {}, XX = {};
    const int mg = m0 + wm * 32 + l31;
    const float Qm = *(const float*)(Qb + 4 * mg);

    // ---- phase A: issue G0(mc)->Bn2; scoreK0 from Bc (phiK0)
    stageG(m0, Bn2);
    __builtin_amdgcn_s_setprio(1);
#pragma unroll
    for (int kt = 0; kt < 4; ++kt) {
      int gb = (((kt * 2 + lh5) ^ bswz) << 4);
      i32x4 bh = *(const i32x4*)(Bc + brow * 128 + gb);
      i32x4 bl = *(const i32x4*)(Bc + 16384 + brow * 128 + gb);
      HH = MFMAI8(TH[kt], bh, HH);
      XX = MFMAI8(TH[kt], bl, XX);
      XX = MFMAI8(TL[kt], bh, XX);
    }
    __builtin_amdgcn_s_setprio(0);
    WAITV(4); PBAR;

    // ---- phase B: issue G1(mc)->Bc; scoreK1 from Bn (phiK1); softmax -> Pb
    stageG(m0 + 64, Bc);
    __builtin_amdgcn_s_setprio(1);
#pragma unroll
    for (int kt = 0; kt < 4; ++kt) {
      int gb = (((kt * 2 + lh5) ^ bswz) << 4);
      i32x4 bh = *(const i32x4*)(Bn + brow * 128 + gb);
      i32x4 bl = *(const i32x4*)(Bn + 16384 + brow * 128 + gb);
      HH = MFMAI8(TH[4 + kt], bh, HH);
      XX = MFMAI8(TH[4 + kt], bl, XX);
      XX = MFMAI8(TL[4 + kt], bh, XX);
    }
    __builtin_amdgcn_s_setprio(0);
    {
      const int pcol = wm * 32 + l31;
      const int gP = pcol >> 3, bP = (pcol & 7) << 1;
      int dyi = ntile - (mg >> 6);
      float dy2 = (float)(dyi * dyi);
#pragma unroll
      for (int r = 0; r < 16; ++r) {
        int prow = wn * 32 + (r & 3) + 8 * (r >> 2) + 4 * lh5;
        float bs = score_d2(HH[r], XX[r], dx2f[r] + dy2);
        float pv = fast_exp2(bs - Qm);
        *(ush*)(Pb + prow * 256 + (((gP ^ (prow & 15)) << 4)) + bP) = f2bf(pv);
      }
    }
    WAITVL(4); PBAR;   // G0 done; P visible

    // ---- phase C: issue phiK0(mc+1)->Bn; PV half 0 from Bn2 (G0)
    if (mc < 31) stagePhi(m0 + 128, 0, Bn);
    __builtin_amdgcn_s_setprio(1);
#pragma unroll
    for (int t2 = 0; t2 < 4; ++t2) {
      int gG = (((t2 * 2 + lh5) ^ gswz) << 4);
      short8 gb = *(const short8*)(Bn2 + grow * 128 + gG);
      {
        int gP0 = ((((t2 * 2 + lh5) ^ (l31 & 15)) << 4));
        short8 pa = *(const short8*)(Pb + l31 * 256 + gP0);
        oacc0 = MFMABF(pa, gb, oacc0);
      }
      {
        int ar = 32 + l31;
        int gP1 = ((((t2 * 2 + lh5) ^ (ar & 15)) << 4));
        short8 pa = *(const short8*)(Pb + ar * 256 + gP1);
        oacc1 = MFMABF(pa, gb, oacc1);
      }
    }
    __builtin_amdgcn_s_setprio(0);
    if (mc < 31) { WAITV(4); } else { WAITV(0); }
    PBAR;

    // ---- phase D: issue phiK1(mc+1)->Bn2; PV half 1 from Bc (G1)
    if (mc < 31) stagePhi(m0 + 128, 1, Bn2);
    __builtin_amdgcn_s_setprio(1);
#pragma unroll
    for (int t2 = 0; t2 < 4; ++t2) {
      int gG = (((t2 * 2 + lh5) ^ gswz) << 4);
      short8 gb = *(const short8*)(Bc + grow * 128 + gG);
      {
        int gP0 = ((((8 + t2 * 2 + lh5) ^ (l31 & 15)) << 4));
        short8 pa = *(const short8*)(Pb + l31 * 256 + gP0);
        oacc0 = MFMABF(pa, gb, oacc0);
      }
      {
        int ar = 32 + l31;
        int gP1 = ((((8 + t2 * 2 + lh5) ^ (ar & 15)) << 4));
        short8 pa = *(const short8*)(Pb + ar * 256 + gP1);
        oacc1 = MFMABF(pa, gb, oacc1);
      }
    }
    __builtin_amdgcn_s_setprio(0);
    if (mc < 31) { WAITV(4); } else { WAITV(0); }
    PBAR;

    char* t = Bc; Bc = Bn; Bn = Bn2; Bn2 = t;
  }

  // epilogue: transpose [n][c] -> [c][n] via LDS, residual, store
  float* Tr = (float*)lds;   // [256 c][65]
  const int c = w * 32 + l31;
#pragma unroll
  for (int r = 0; r < 16; ++r) {
    int crow = (r & 3) + 8 * (r >> 2) + 4 * lh5;
    Tr[c * 65 + crow] = oacc0[r];
    Tr[c * 65 + 32 + crow] = oacc1[r];
  }
  __syncthreads();
  const float* xb = x + (size_t)b * C * N;
  float* ob = out + (size_t)b * C * N;
  for (int e = tid; e < 16384; e += 512) {
    int cc = e >> 6, nl = e & 63;
    size_t idx = (size_t)cc * N + n0 + nl;
    ob[idx] = Tr[cc * 65 + nl] + xb[idx];
  }
}

extern "C" void kernel_launch(void* const* d_in, const int* in_sizes, int n_in,
                              void* d_out, int out_size, void* d_ws, size_t ws_size,
                              hipStream_t stream) {
  const float* x       = (const float*)d_in[0];
  const float* w_phi   = (const float*)d_in[1];
  const float* w_theta = (const float*)d_in[2];
  const float* w_g     = (const float*)d_in[3];
  float* out = (float*)d_out;
  char* wsu8 = (char*)d_ws;                      // ~24.3 MB used
  float* fws = (float*)(wsu8 + FOFF);

  proj_kernel<<<dim3(256, 12), 256, 0, stream>>>(x, w_phi, w_theta, w_g, wsu8);
  stats_kernel<<<dim3(32, NCH, B), 512, 0, stream>>>(wsu8, fws);
  finalize_stats<<<dim3(B * N / 256), 256, 0, stream>>>(fws);
  out_kernel<<<dim3(64, B), 512, 0, stream>>>(x, out, wsu8, fws);
}